// Round 2
// baseline (209.792 us; speedup 1.0000x reference)
//
#include <hip/hip_runtime.h>
#include <math.h>

// ---------------------------------------------------------------------------
// HROMAttention: x(4,2048,512) -> QKV(+bias) -> RoPE -> MHA(8 heads, d=64)
//                -> proj(+bias). All GEMMs bf16 MFMA 16x16x32, fp32 accum.
// Round 4: split-K flash attention (2 KV-splits) to lift occupancy.
//   Grid was 512 blocks = 2 blocks/CU = 16 waves/CU (50% cap, measured 40%);
//   resources (VGPR 44, LDS 32KB) allow 4 blocks/CU. Split the 2048-key range
//   into 2 halves -> 1024 blocks -> 32 waves/CU. Blocks write unnormalized
//   O (f32) + (m,l) per q; combine kernel merges. Falls back to single-pass
//   attn if ws_size is too small for the partial buffers.
// ws layout (bytes):
//   [0)         xb     bf16 8192x512     8388608
//   [8388608)   wqb    bf16 1536x512     1572864
//   [9961472)   wpb    bf16  512x512      524288
//   [10485760)  cosT   f32  2048x32       262144
//   [10747904)  sinT   f32  2048x32       262144
//   [11010048)  Qb     bf16 (b,h,t,d)    8388608   (pre-scaled by 0.125*log2e)
//   [19398656)  Kb     bf16 (b,h,t,d)    8388608
//   [27787264)  Vtb    bf16 (b,h,d,t)    8388608
//   [36175872)  attnb  bf16 8192x512     8388608
//   [44564480)  Opart  f32  2x65536x64  33554432   (split-K partial O)
//   [78118912)  ml     f32  2x65536x2    1048576   (split-K partial m,l)
// total 79167488 B (~75.5 MB) of d_ws (guarded; falls back at 44.6 MB)
// ---------------------------------------------------------------------------

typedef __attribute__((ext_vector_type(8))) short bf16x8;
typedef __attribute__((ext_vector_type(4))) float floatx4;

#define LOG2E 1.44269504088896f

__device__ __forceinline__ unsigned short f2bf(float f) {
  unsigned int u = __float_as_uint(f);
  u += 0x7fffu + ((u >> 16) & 1u);   // round-to-nearest-even
  return (unsigned short)(u >> 16);
}

// pack two f32 -> bf16x2 (low16 = a, high16 = b), RNE, single VALU inst
__device__ __forceinline__ unsigned int cvtpk_bf16(float a, float b) {
  unsigned int r;
  asm("v_cvt_pk_bf16_f32 %0, %1, %2" : "=v"(r) : "v"(a), "v"(b));
  return r;
}

__device__ __forceinline__ void gld_lds16(unsigned short* lds, const unsigned short* g) {
  __builtin_amdgcn_global_load_lds(
      (const __attribute__((address_space(1))) unsigned int*)g,
      (__attribute__((address_space(3))) unsigned int*)lds, 16, 0, 0);
}

// ---------------------------------------------------------------------------
// prep: bf16 conversions + RoPE cos/sin table (fp64 trig for accuracy)
// ---------------------------------------------------------------------------
__global__ __launch_bounds__(256) void prep_kernel(
    const float* __restrict__ x, const float* __restrict__ wq, const float* __restrict__ wp,
    unsigned short* __restrict__ xb, unsigned short* __restrict__ wqb,
    unsigned short* __restrict__ wpb, float* __restrict__ cosT, float* __restrict__ sinT) {
  int i = blockIdx.x * 256 + threadIdx.x;
  if (i < 4194304) {
    xb[i] = f2bf(x[i]);
  } else if (i < 4980736) {
    int j = i - 4194304; wqb[j] = f2bf(wq[j]);
  } else if (i < 5242880) {
    int j = i - 4980736; wpb[j] = f2bf(wp[j]);
  } else if (i < 5308416) {
    int j = i - 5242880;
    int t = j >> 5, f = j & 31;
    double fr = (double)t * pow(10000.0, -(double)f / 32.0);
    cosT[j] = (float)cos(fr);
    sinT[j] = (float)sin(fr);
  }
}

// ---------------------------------------------------------------------------
// QKV GEMM: xb(8192x512) @ wqb(1536x512)^T + bias, epilogue RoPE + scatter
// 128x128 tile, BK=32, 4 waves each 64x64 (4x4 m/n tiles of 16x16)
// ---------------------------------------------------------------------------
__global__ __launch_bounds__(256) void qkv_kernel(
    const unsigned short* __restrict__ xb, const unsigned short* __restrict__ wqb,
    const float* __restrict__ qkv_b, const float* __restrict__ cosT,
    const float* __restrict__ sinT, unsigned short* __restrict__ Qb,
    unsigned short* __restrict__ Kb, unsigned short* __restrict__ Vtb) {
  __shared__ __align__(16) unsigned short As[128 * 32];
  __shared__ __align__(16) unsigned short Bs[128 * 32];
  const int tid = threadIdx.x;
  const int wave = tid >> 6, lane = tid & 63, ln = lane & 15, quad = lane >> 4;
  const int m0 = blockIdx.x * 128, n0 = blockIdx.y * 128;
  const int wr = (wave >> 1) * 64, wc = (wave & 1) * 64;

  floatx4 acc[4][4];
#pragma unroll
  for (int i = 0; i < 4; ++i)
#pragma unroll
    for (int j = 0; j < 4; ++j) acc[i][j] = (floatx4){0.f, 0.f, 0.f, 0.f};

  const int c0 = tid, c1 = tid + 256;
  const int ar0 = c0 >> 2, ak0 = (c0 & 3) * 8;
  const int ar1 = c1 >> 2, ak1 = (c1 & 3) * 8;

  for (int k0 = 0; k0 < 512; k0 += 32) {
    __syncthreads();
    gld_lds16(As + c0 * 8, xb + (size_t)(m0 + ar0) * 512 + k0 + ak0);
    gld_lds16(As + c1 * 8, xb + (size_t)(m0 + ar1) * 512 + k0 + ak1);
    gld_lds16(Bs + c0 * 8, wqb + (size_t)(n0 + ar0) * 512 + k0 + ak0);
    gld_lds16(Bs + c1 * 8, wqb + (size_t)(n0 + ar1) * 512 + k0 + ak1);
    __syncthreads();
    bf16x8 af[4], bfb[4];
#pragma unroll
    for (int mi = 0; mi < 4; ++mi)
      af[mi] = *(const bf16x8*)(As + (wr + mi * 16 + ln) * 32 + quad * 8);
#pragma unroll
    for (int ni = 0; ni < 4; ++ni)
      bfb[ni] = *(const bf16x8*)(Bs + (wc + ni * 16 + ln) * 32 + quad * 8);
#pragma unroll
    for (int mi = 0; mi < 4; ++mi)
#pragma unroll
      for (int ni = 0; ni < 4; ++ni)
        acc[mi][ni] = __builtin_amdgcn_mfma_f32_16x16x32_bf16(af[mi], bfb[ni], acc[mi][ni], 0, 0, 0);
  }

  // epilogue: wave's 64 cols lie in exactly one (mat, head)
  const int colbase = n0 + wc;                    // multiple of 64
  const int mat = colbase >> 9;                   // 0=q 1=k 2=v
  const int h = (colbase & 511) >> 6;
  float bias[4];
#pragma unroll
  for (int ni = 0; ni < 4; ++ni) bias[ni] = qkv_b[colbase + ni * 16 + ln];

  if (mat == 2) {
    // V: store transposed (b,h,d,t); lane holds 4 consecutive t at fixed d
#pragma unroll
    for (int mi = 0; mi < 4; ++mi) {
      int row0 = m0 + wr + mi * 16 + quad * 4;
      int bidx = row0 >> 11, t = row0 & 2047;
#pragma unroll
      for (int ni = 0; ni < 4; ++ni) {
        int d = ni * 16 + ln;
        ushort4 pk;
        pk.x = f2bf(acc[mi][ni][0] + bias[ni]);
        pk.y = f2bf(acc[mi][ni][1] + bias[ni]);
        pk.z = f2bf(acc[mi][ni][2] + bias[ni]);
        pk.w = f2bf(acc[mi][ni][3] + bias[ni]);
        *(ushort4*)(Vtb + ((size_t)(bidx * 8 + h) * 64 + d) * 2048 + t) = pk;
      }
    }
  } else {
    // Q/K: in-register RoPE — pair (d, d+32) = acc tiles (ni, ni+2), same lane
    unsigned short* dst = (mat == 0) ? Qb : Kb;
    // fold 1/sqrt(64) AND log2(e) (exp2-domain softmax) into Q
    const float sc = (mat == 0) ? 0.125f * LOG2E : 1.0f;
#pragma unroll
    for (int mi = 0; mi < 4; ++mi) {
#pragma unroll
      for (int r = 0; r < 4; ++r) {
        int row = m0 + wr + mi * 16 + quad * 4 + r;
        int bidx = row >> 11, t = row & 2047;
        const float* cr = cosT + t * 32;
        const float* sr = sinT + t * 32;
        size_t obase = ((size_t)(bidx * 8 + h) * 2048 + t) * 64;
#pragma unroll
        for (int ni = 0; ni < 2; ++ni) {
          int dlo = ni * 16 + ln;
          float cv = cr[dlo], sv = sr[dlo];
          float xlo = acc[mi][ni][r] + bias[ni];
          float xhi = acc[mi][ni + 2][r] + bias[ni + 2];
          dst[obase + dlo]      = f2bf((xlo * cv - xhi * sv) * sc);
          dst[obase + dlo + 32] = f2bf((xhi * cv + xlo * sv) * sc);
        }
      }
    }
  }
}

// ---------------------------------------------------------------------------
// Split-K transposed flash attention (2 splits of 1024 keys):
//   block = 128 q x one (b,h,split); 8 waves x 16 q; K-tile = 64.
//   Same inner structure as round 3 (S^T = K·Q^T, XOR-swizzled LDS,
//   cvt_pk P-pack, defer-rescale). Epilogue writes unnormalized O (f32)
//   and per-q (m,l) for the combine kernel.
// ---------------------------------------------------------------------------
__global__ __launch_bounds__(512) void attn_sk_kernel(
    const unsigned short* __restrict__ Qb, const unsigned short* __restrict__ Kb,
    const unsigned short* __restrict__ Vtb, const float* __restrict__ mask,
    float* __restrict__ Opart, float* __restrict__ ml) {
  __shared__ __align__(16) unsigned short Ks[64 * 64];   // (t_k, d)   swizzled
  __shared__ __align__(16) unsigned short Vs[64 * 64];   // (d, t_k)   swizzled
  __shared__ __align__(16) unsigned short Ps[128 * 64];  // (q, t_k)   swizzled

  const int tid = threadIdx.x;
  const int wave = tid >> 6, lane = tid & 63, ln = lane & 15, quad = lane >> 4;
  const int swz = (ln & 7) << 3;
  const int by = blockIdx.y;
  const int bh = by >> 1, split = by & 1;
  const int b = bh >> 3, h = bh & 7;
  const int q0 = blockIdx.x * 128;
  const int wq = wave * 16;
  const int kbeg = split * 1024, kend = kbeg + 1024;
  (void)h;

  const unsigned short* Qhead = Qb + (size_t)bh * 2048 * 64;
  const unsigned short* Khead = Kb + (size_t)bh * 2048 * 64;
  const unsigned short* Vhead = Vtb + (size_t)bh * 64 * 2048;

  bf16x8 qf[2];
#pragma unroll
  for (int ks = 0; ks < 2; ++ks)
    qf[ks] = *(const bf16x8*)(Qhead + (size_t)(q0 + wq + ln) * 64 + ks * 32 + quad * 8);

  floatx4 o[4];
#pragma unroll
  for (int mi2 = 0; mi2 < 4; ++mi2) o[mi2] = (floatx4){0.f, 0.f, 0.f, 0.f};
  float mrun = -INFINITY;
  float lrun = 0.f;

  const int srow = tid >> 3;
  const int scol = (tid & 7) * 8;
  const int sdst = srow * 64 + (scol ^ ((srow & 7) << 3));
  uint4 kpre = *(const uint4*)(Khead + (size_t)(kbeg + srow) * 64 + scol);
  uint4 vpre = *(const uint4*)(Vhead + (size_t)srow * 2048 + kbeg + scol);

  for (int k0 = kbeg; k0 < kend; k0 += 64) {
    __syncthreads();
    *(uint4*)(Ks + sdst) = kpre;
    *(uint4*)(Vs + sdst) = vpre;
    __syncthreads();
    if (k0 + 64 < kend) {
      kpre = *(const uint4*)(Khead + (size_t)(k0 + 64 + srow) * 64 + scol);
      vpre = *(const uint4*)(Vhead + (size_t)srow * 2048 + k0 + 64 + scol);
    }

    floatx4 sm[4];
#pragma unroll
    for (int mi = 0; mi < 4; ++mi) {
      bf16x8 kf0 = *(const bf16x8*)(Ks + (mi * 16 + ln) * 64 + ((quad * 8) ^ swz));
      bf16x8 kf1 = *(const bf16x8*)(Ks + (mi * 16 + ln) * 64 + ((32 + quad * 8) ^ swz));
      floatx4 a = (floatx4){0.f, 0.f, 0.f, 0.f};
      a = __builtin_amdgcn_mfma_f32_16x16x32_bf16(kf0, qf[0], a, 0, 0, 0);
      a = __builtin_amdgcn_mfma_f32_16x16x32_bf16(kf1, qf[1], a, 0, 0, 0);
      sm[mi] = a;
    }
#pragma unroll
    for (int mi = 0; mi < 4; ++mi) {
      float4 mv = *(const float4*)(mask + b * 2048 + k0 + mi * 16 + quad * 4);
      sm[mi][0] += mv.x * LOG2E; sm[mi][1] += mv.y * LOG2E;
      sm[mi][2] += mv.z * LOG2E; sm[mi][3] += mv.w * LOG2E;
    }
    float vmax = fmaxf(fmaxf(sm[0][0], sm[0][1]), fmaxf(sm[0][2], sm[0][3]));
#pragma unroll
    for (int mi = 1; mi < 4; ++mi)
      vmax = fmaxf(vmax, fmaxf(fmaxf(sm[mi][0], sm[mi][1]), fmaxf(sm[mi][2], sm[mi][3])));
    vmax = fmaxf(vmax, __shfl_xor(vmax, 16));
    vmax = fmaxf(vmax, __shfl_xor(vmax, 32));
    if (__any(vmax > mrun)) {
      float nm = fmaxf(mrun, vmax);
      float alpha = exp2f(mrun - nm);
      mrun = nm;
      lrun *= alpha;
#pragma unroll
      for (int mi2 = 0; mi2 < 4; ++mi2) {
        o[mi2][0] *= alpha; o[mi2][1] *= alpha;
        o[mi2][2] *= alpha; o[mi2][3] *= alpha;
      }
    }
    float psum = 0.f;
#pragma unroll
    for (int mi = 0; mi < 4; ++mi)
#pragma unroll
      for (int r = 0; r < 4; ++r) {
        float p = exp2f(sm[mi][r] - mrun);
        sm[mi][r] = p;
        psum += p;
      }
    psum += __shfl_xor(psum, 16);
    psum += __shfl_xor(psum, 32);
    lrun += psum;

#pragma unroll
    for (int mi = 0; mi < 4; ++mi) {
      uint2 pk;
      pk.x = cvtpk_bf16(sm[mi][0], sm[mi][1]);
      pk.y = cvtpk_bf16(sm[mi][2], sm[mi][3]);
      *(uint2*)(Ps + (wq + ln) * 64 + ((mi * 16 + quad * 4) ^ swz)) = pk;
    }
#pragma unroll
    for (int ks = 0; ks < 2; ++ks) {
      bf16x8 pb = *(const bf16x8*)(Ps + (wq + ln) * 64 + ((ks * 32 + quad * 8) ^ swz));
#pragma unroll
      for (int mi2 = 0; mi2 < 4; ++mi2) {
        bf16x8 vf = *(const bf16x8*)(Vs + (mi2 * 16 + ln) * 64 + ((ks * 32 + quad * 8) ^ swz));
        o[mi2] = __builtin_amdgcn_mfma_f32_16x16x32_bf16(vf, pb, o[mi2], 0, 0, 0);
      }
    }
  }

  // epilogue: unnormalized O + (m,l) partials
  {
    int t = q0 + wq + ln;
    size_t qi = (size_t)bh * 2048 + t;
    float* ob = Opart + ((size_t)split * 65536 + qi) * 64;
#pragma unroll
    for (int mi2 = 0; mi2 < 4; ++mi2)
      *(floatx4*)(ob + mi2 * 16 + quad * 4) = o[mi2];
    if (quad == 0) {
      float2 v; v.x = mrun; v.y = lrun;
      *(float2*)(ml + ((size_t)split * 65536 + qi) * 2) = v;
    }
  }
}

// ---------------------------------------------------------------------------
// combine: merge 2 split-K partials -> attnb bf16. One thread = (q, 16 d).
// ---------------------------------------------------------------------------
__global__ __launch_bounds__(256) void combine_kernel(
    const float* __restrict__ Opart, const float* __restrict__ ml,
    unsigned short* __restrict__ attnb) {
  int g = blockIdx.x * 256 + threadIdx.x;        // 262144 total
  int qi = g >> 2, dq = (g & 3) * 16;
  float2 a = *(const float2*)(ml + (size_t)qi * 2);
  float2 c = *(const float2*)(ml + (size_t)(65536 + qi) * 2);
  float m = fmaxf(a.x, c.x);
  float w0 = exp2f(a.x - m), w1 = exp2f(c.x - m);
  float inv = 1.f / (a.y * w0 + c.y * w1);
  float s0 = w0 * inv, s1 = w1 * inv;
  const float* p0 = Opart + (size_t)qi * 64 + dq;
  const float* p1 = Opart + (size_t)(65536 + qi) * 64 + dq;
  int bh = qi >> 11, t = qi & 2047, b = bh >> 3, h = bh & 7;
  unsigned short* dst = attnb + ((size_t)b * 2048 + t) * 512 + h * 64 + dq;
  unsigned int r[8];
#pragma unroll
  for (int j = 0; j < 4; ++j) {
    float4 x0 = *(const float4*)(p0 + j * 4);
    float4 x1 = *(const float4*)(p1 + j * 4);
    float f0 = x0.x * s0 + x1.x * s1;
    float f1 = x0.y * s0 + x1.y * s1;
    float f2 = x0.z * s0 + x1.z * s1;
    float f3 = x0.w * s0 + x1.w * s1;
    r[2 * j]     = cvtpk_bf16(f0, f1);
    r[2 * j + 1] = cvtpk_bf16(f2, f3);
  }
  *(uint4*)(dst)     = make_uint4(r[0], r[1], r[2], r[3]);
  *(uint4*)(dst + 8) = make_uint4(r[4], r[5], r[6], r[7]);
}

// ---------------------------------------------------------------------------
// Fallback single-pass attention (round-3 kernel) — used if ws too small.
// ---------------------------------------------------------------------------
__global__ __launch_bounds__(512) void attn_kernel(
    const unsigned short* __restrict__ Qb, const unsigned short* __restrict__ Kb,
    const unsigned short* __restrict__ Vtb, const float* __restrict__ mask,
    unsigned short* __restrict__ attnb) {
  __shared__ __align__(16) unsigned short Ks[64 * 64];
  __shared__ __align__(16) unsigned short Vs[64 * 64];
  __shared__ __align__(16) unsigned short Ps[128 * 64];

  const int tid = threadIdx.x;
  const int wave = tid >> 6, lane = tid & 63, ln = lane & 15, quad = lane >> 4;
  const int swz = (ln & 7) << 3;
  const int bh = blockIdx.y;
  const int b = bh >> 3, h = bh & 7;
  const int q0 = blockIdx.x * 128;
  const int wq = wave * 16;

  const unsigned short* Qhead = Qb + (size_t)bh * 2048 * 64;
  const unsigned short* Khead = Kb + (size_t)bh * 2048 * 64;
  const unsigned short* Vhead = Vtb + (size_t)bh * 64 * 2048;

  bf16x8 qf[2];
#pragma unroll
  for (int ks = 0; ks < 2; ++ks)
    qf[ks] = *(const bf16x8*)(Qhead + (size_t)(q0 + wq + ln) * 64 + ks * 32 + quad * 8);

  floatx4 o[4];
#pragma unroll
  for (int mi2 = 0; mi2 < 4; ++mi2) o[mi2] = (floatx4){0.f, 0.f, 0.f, 0.f};
  float mrun = -INFINITY;
  float lrun = 0.f;

  const int srow = tid >> 3;
  const int scol = (tid & 7) * 8;
  const int sdst = srow * 64 + (scol ^ ((srow & 7) << 3));
  uint4 kpre = *(const uint4*)(Khead + (size_t)srow * 64 + scol);
  uint4 vpre = *(const uint4*)(Vhead + (size_t)srow * 2048 + scol);

  for (int k0 = 0; k0 < 2048; k0 += 64) {
    __syncthreads();
    *(uint4*)(Ks + sdst) = kpre;
    *(uint4*)(Vs + sdst) = vpre;
    __syncthreads();
    if (k0 + 64 < 2048) {
      kpre = *(const uint4*)(Khead + (size_t)(k0 + 64 + srow) * 64 + scol);
      vpre = *(const uint4*)(Vhead + (size_t)srow * 2048 + k0 + 64 + scol);
    }

    floatx4 sm[4];
#pragma unroll
    for (int mi = 0; mi < 4; ++mi) {
      bf16x8 kf0 = *(const bf16x8*)(Ks + (mi * 16 + ln) * 64 + ((quad * 8) ^ swz));
      bf16x8 kf1 = *(const bf16x8*)(Ks + (mi * 16 + ln) * 64 + ((32 + quad * 8) ^ swz));
      floatx4 a = (floatx4){0.f, 0.f, 0.f, 0.f};
      a = __builtin_amdgcn_mfma_f32_16x16x32_bf16(kf0, qf[0], a, 0, 0, 0);
      a = __builtin_amdgcn_mfma_f32_16x16x32_bf16(kf1, qf[1], a, 0, 0, 0);
      sm[mi] = a;
    }
#pragma unroll
    for (int mi = 0; mi < 4; ++mi) {
      float4 mv = *(const float4*)(mask + b * 2048 + k0 + mi * 16 + quad * 4);
      sm[mi][0] += mv.x * LOG2E; sm[mi][1] += mv.y * LOG2E;
      sm[mi][2] += mv.z * LOG2E; sm[mi][3] += mv.w * LOG2E;
    }
    float vmax = fmaxf(fmaxf(sm[0][0], sm[0][1]), fmaxf(sm[0][2], sm[0][3]));
#pragma unroll
    for (int mi = 1; mi < 4; ++mi)
      vmax = fmaxf(vmax, fmaxf(fmaxf(sm[mi][0], sm[mi][1]), fmaxf(sm[mi][2], sm[mi][3])));
    vmax = fmaxf(vmax, __shfl_xor(vmax, 16));
    vmax = fmaxf(vmax, __shfl_xor(vmax, 32));
    if (__any(vmax > mrun)) {
      float nm = fmaxf(mrun, vmax);
      float alpha = exp2f(mrun - nm);
      mrun = nm;
      lrun *= alpha;
#pragma unroll
      for (int mi2 = 0; mi2 < 4; ++mi2) {
        o[mi2][0] *= alpha; o[mi2][1] *= alpha;
        o[mi2][2] *= alpha; o[mi2][3] *= alpha;
      }
    }
    float psum = 0.f;
#pragma unroll
    for (int mi = 0; mi < 4; ++mi)
#pragma unroll
      for (int r = 0; r < 4; ++r) {
        float p = exp2f(sm[mi][r] - mrun);
        sm[mi][r] = p;
        psum += p;
      }
    psum += __shfl_xor(psum, 16);
    psum += __shfl_xor(psum, 32);
    lrun += psum;

#pragma unroll
    for (int mi = 0; mi < 4; ++mi) {
      uint2 pk;
      pk.x = cvtpk_bf16(sm[mi][0], sm[mi][1]);
      pk.y = cvtpk_bf16(sm[mi][2], sm[mi][3]);
      *(uint2*)(Ps + (wq + ln) * 64 + ((mi * 16 + quad * 4) ^ swz)) = pk;
    }
#pragma unroll
    for (int ks = 0; ks < 2; ++ks) {
      bf16x8 pb = *(const bf16x8*)(Ps + (wq + ln) * 64 + ((ks * 32 + quad * 8) ^ swz));
#pragma unroll
      for (int mi2 = 0; mi2 < 4; ++mi2) {
        bf16x8 vf = *(const bf16x8*)(Vs + (mi2 * 16 + ln) * 64 + ((ks * 32 + quad * 8) ^ swz));
        o[mi2] = __builtin_amdgcn_mfma_f32_16x16x32_bf16(vf, pb, o[mi2], 0, 0, 0);
      }
    }
  }

  {
    float inv = 1.f / lrun;
    int t = q0 + wq + ln;
    size_t base = ((size_t)b * 2048 + t) * 512 + h * 64;
#pragma unroll
    for (int mi2 = 0; mi2 < 4; ++mi2) {
      uint2 pk;
      pk.x = cvtpk_bf16(o[mi2][0] * inv, o[mi2][1] * inv);
      pk.y = cvtpk_bf16(o[mi2][2] * inv, o[mi2][3] * inv);
      *(uint2*)(attnb + base + mi2 * 16 + quad * 4) = pk;
    }
  }
}

// ---------------------------------------------------------------------------
// proj GEMM: attnb(8192x512) @ wpb(512x512)^T + bias -> out fp32
// ---------------------------------------------------------------------------
__global__ __launch_bounds__(256) void proj_kernel(
    const unsigned short* __restrict__ ab, const unsigned short* __restrict__ wpb,
    const float* __restrict__ proj_b, float* __restrict__ out) {
  __shared__ __align__(16) unsigned short As[128 * 32];
  __shared__ __align__(16) unsigned short Bs[128 * 32];
  const int tid = threadIdx.x;
  const int wave = tid >> 6, lane = tid & 63, ln = lane & 15, quad = lane >> 4;
  const int m0 = blockIdx.x * 128, n0 = blockIdx.y * 128;
  const int wr = (wave >> 1) * 64, wc = (wave & 1) * 64;

  floatx4 acc[4][4];
#pragma unroll
  for (int i = 0; i < 4; ++i)
#pragma unroll
    for (int j = 0; j < 4; ++j) acc[i][j] = (floatx4){0.f, 0.f, 0.f, 0.f};

  const int c0 = tid, c1 = tid + 256;
  const int ar0 = c0 >> 2, ak0 = (c0 & 3) * 8;
  const int ar1 = c1 >> 2, ak1 = (c1 & 3) * 8;

  for (int k0 = 0; k0 < 512; k0 += 32) {
    __syncthreads();
    gld_lds16(As + c0 * 8, ab + (size_t)(m0 + ar0) * 512 + k0 + ak0);
    gld_lds16(As + c1 * 8, ab + (size_t)(m0 + ar1) * 512 + k0 + ak1);
    gld_lds16(Bs + c0 * 8, wpb + (size_t)(n0 + ar0) * 512 + k0 + ak0);
    gld_lds16(Bs + c1 * 8, wpb + (size_t)(n0 + ar1) * 512 + k0 + ak1);
    __syncthreads();
    bf16x8 af[4], bfb[4];
#pragma unroll
    for (int mi = 0; mi < 4; ++mi)
      af[mi] = *(const bf16x8*)(As + (wr + mi * 16 + ln) * 32 + quad * 8);
#pragma unroll
    for (int ni = 0; ni < 4; ++ni)
      bfb[ni] = *(const bf16x8*)(Bs + (wc + ni * 16 + ln) * 32 + quad * 8);
#pragma unroll
    for (int mi = 0; mi < 4; ++mi)
#pragma unroll
      for (int ni = 0; ni < 4; ++ni)
        acc[mi][ni] = __builtin_amdgcn_mfma_f32_16x16x32_bf16(af[mi], bfb[ni], acc[mi][ni], 0, 0, 0);
  }

#pragma unroll
  for (int mi = 0; mi < 4; ++mi)
#pragma unroll
    for (int ni = 0; ni < 4; ++ni) {
      int col = n0 + wc + ni * 16 + ln;
      float pb = proj_b[col];
#pragma unroll
      for (int r = 0; r < 4; ++r) {
        int row = m0 + wr + mi * 16 + quad * 4 + r;
        out[(size_t)row * 512 + col] = acc[mi][ni][r] + pb;
      }
    }
}

// ---------------------------------------------------------------------------
extern "C" void kernel_launch(void* const* d_in, const int* in_sizes, int n_in,
                              void* d_out, int out_size, void* d_ws, size_t ws_size,
                              hipStream_t stream) {
  const float* x      = (const float*)d_in[0];
  const float* mask   = (const float*)d_in[1];
  const float* qkv_w  = (const float*)d_in[2];
  const float* qkv_b  = (const float*)d_in[3];
  const float* proj_w = (const float*)d_in[4];
  const float* proj_b = (const float*)d_in[5];
  float* out = (float*)d_out;

  char* ws = (char*)d_ws;
  unsigned short* xb   = (unsigned short*)(ws);
  unsigned short* wqb  = (unsigned short*)(ws + 8388608);
  unsigned short* wpb  = (unsigned short*)(ws + 9961472);
  float* cosT          = (float*)(ws + 10485760);
  float* sinT          = (float*)(ws + 10747904);
  unsigned short* Qb   = (unsigned short*)(ws + 11010048);
  unsigned short* Kb   = (unsigned short*)(ws + 19398656);
  unsigned short* Vtb  = (unsigned short*)(ws + 27787264);
  unsigned short* attnb= (unsigned short*)(ws + 36175872);
  float* Opart         = (float*)(ws + 44564480);
  float* ml            = (float*)(ws + 78118912);

  prep_kernel<<<20736, 256, 0, stream>>>(x, qkv_w, proj_w, xb, wqb, wpb, cosT, sinT);
  dim3 g1(64, 12);
  qkv_kernel<<<g1, 256, 0, stream>>>(xb, wqb, qkv_b, cosT, sinT, Qb, Kb, Vtb);
  if (ws_size >= 79167488) {
    dim3 g2(16, 64);
    attn_sk_kernel<<<g2, 512, 0, stream>>>(Qb, Kb, Vtb, mask, Opart, ml);
    combine_kernel<<<1024, 256, 0, stream>>>(Opart, ml, attnb);
  } else {
    dim3 g2(16, 32);
    attn_kernel<<<g2, 512, 0, stream>>>(Qb, Kb, Vtb, mask, attnb);
  }
  dim3 g3(64, 4);
  proj_kernel<<<g3, 256, 0, stream>>>(attnb, wpb, proj_b, out);
}

// Round 4
// 196.835 us; speedup vs baseline: 1.0658x; 1.0658x over previous
//
#include <hip/hip_runtime.h>
#include <math.h>

// ---------------------------------------------------------------------------
// HROMAttention: x(4,2048,512) -> QKV(+bias) -> RoPE -> MHA(8 heads, d=64)
//                -> proj(+bias). All GEMMs bf16 MFMA 16x16x32, fp32 accum.
// Round 5 (resubmit; prior bench was an infra failure, not a kernel error):
//   attn = round-3 single-pass (split-K regressed: residency pinned ~2 wg/CU
//   regardless of grid). GEMMs get T3 "minimum 2-phase" pipeline: double-
//   buffered LDS, next-tile global_load_lds issued BEFORE current-tile
//   compute, ONE barrier per K-step. proj at 512 threads (8 waves; grid is
//   only 256 blocks = 1 block/CU). prep vectorized 8 elems/thread.
// ws layout (bytes):
//   [0)         xb     bf16 8192x512     8388608
//   [8388608)   wqb    bf16 1536x512     1572864
//   [9961472)   wpb    bf16  512x512      524288
//   [10485760)  cosT   f32  2048x32       262144
//   [10747904)  sinT   f32  2048x32       262144
//   [11010048)  Qb     bf16 (b,h,t,d)    8388608   (pre-scaled by 0.125*log2e)
//   [19398656)  Kb     bf16 (b,h,t,d)    8388608
//   [27787264)  Vtb    bf16 (b,h,d,t)    8388608
//   [36175872)  attnb  bf16 8192x512     8388608
// total 44564480 B (~42.5 MB) of d_ws
// ---------------------------------------------------------------------------

typedef __attribute__((ext_vector_type(8))) short bf16x8;
typedef __attribute__((ext_vector_type(4))) float floatx4;

#define LOG2E 1.44269504088896f

__device__ __forceinline__ unsigned short f2bf(float f) {
  unsigned int u = __float_as_uint(f);
  u += 0x7fffu + ((u >> 16) & 1u);   // round-to-nearest-even
  return (unsigned short)(u >> 16);
}

// pack two f32 -> bf16x2 (low16 = a, high16 = b), RNE, single VALU inst
__device__ __forceinline__ unsigned int cvtpk_bf16(float a, float b) {
  unsigned int r;
  asm("v_cvt_pk_bf16_f32 %0, %1, %2" : "=v"(r) : "v"(a), "v"(b));
  return r;
}

__device__ __forceinline__ void gld_lds16(unsigned short* lds, const unsigned short* g) {
  __builtin_amdgcn_global_load_lds(
      (const __attribute__((address_space(1))) unsigned int*)g,
      (__attribute__((address_space(3))) unsigned int*)lds, 16, 0, 0);
}

// ---------------------------------------------------------------------------
// prep: bf16 conversions (8 elems/thread) + RoPE cos/sin table (fp64 trig)
// f32 elements: x 4194304 | wq 786432 | wp 262144  (all /8) -> 655360 threads
// table: 65536 entries, 1/thread -> threads 655360..720895
// ---------------------------------------------------------------------------
__global__ __launch_bounds__(256) void prep_kernel(
    const float* __restrict__ x, const float* __restrict__ wq, const float* __restrict__ wp,
    unsigned short* __restrict__ xb, unsigned short* __restrict__ wqb,
    unsigned short* __restrict__ wpb, float* __restrict__ cosT, float* __restrict__ sinT) {
  int i = blockIdx.x * 256 + threadIdx.x;
  if (i < 655360) {
    int base = i * 8;
    const float* src;
    unsigned short* dst;
    int j;
    if (base < 4194304)      { src = x;  dst = xb;  j = base; }
    else if (base < 4980736) { src = wq; dst = wqb; j = base - 4194304; }
    else                     { src = wp; dst = wpb; j = base - 4980736; }
    float4 a = *(const float4*)(src + j);
    float4 b = *(const float4*)(src + j + 4);
    uint4 r;
    r.x = cvtpk_bf16(a.x, a.y);
    r.y = cvtpk_bf16(a.z, a.w);
    r.z = cvtpk_bf16(b.x, b.y);
    r.w = cvtpk_bf16(b.z, b.w);
    *(uint4*)(dst + j) = r;
  } else if (i < 720896) {
    int j = i - 655360;
    int t = j >> 5, f = j & 31;
    double fr = (double)t * pow(10000.0, -(double)f / 32.0);
    cosT[j] = (float)cos(fr);
    sinT[j] = (float)sin(fr);
  }
}

// ---------------------------------------------------------------------------
// QKV GEMM: xb(8192x512) @ wqb(1536x512)^T + bias, epilogue RoPE + scatter
// 128x128 tile, BK=32, 4 waves each 64x64. 2-phase dbuf pipeline:
// stage(next) issued before compute(cur); one barrier per K-step.
// ---------------------------------------------------------------------------
__global__ __launch_bounds__(256) void qkv_kernel(
    const unsigned short* __restrict__ xb, const unsigned short* __restrict__ wqb,
    const float* __restrict__ qkv_b, const float* __restrict__ cosT,
    const float* __restrict__ sinT, unsigned short* __restrict__ Qb,
    unsigned short* __restrict__ Kb, unsigned short* __restrict__ Vtb) {
  __shared__ __align__(16) unsigned short As[2][128 * 32];
  __shared__ __align__(16) unsigned short Bs[2][128 * 32];
  const int tid = threadIdx.x;
  const int wave = tid >> 6, lane = tid & 63, ln = lane & 15, quad = lane >> 4;
  const int m0 = blockIdx.x * 128, n0 = blockIdx.y * 128;
  const int wr = (wave >> 1) * 64, wc = (wave & 1) * 64;

  floatx4 acc[4][4];
#pragma unroll
  for (int i = 0; i < 4; ++i)
#pragma unroll
    for (int j = 0; j < 4; ++j) acc[i][j] = (floatx4){0.f, 0.f, 0.f, 0.f};

  const int c0 = tid, c1 = tid + 256;
  const int ar0 = c0 >> 2, ak0 = (c0 & 3) * 8;
  const int ar1 = c1 >> 2, ak1 = (c1 & 3) * 8;

  // prologue: stage K-tile 0 into buffer 0
  gld_lds16(As[0] + c0 * 8, xb + (size_t)(m0 + ar0) * 512 + ak0);
  gld_lds16(As[0] + c1 * 8, xb + (size_t)(m0 + ar1) * 512 + ak1);
  gld_lds16(Bs[0] + c0 * 8, wqb + (size_t)(n0 + ar0) * 512 + ak0);
  gld_lds16(Bs[0] + c1 * 8, wqb + (size_t)(n0 + ar1) * 512 + ak1);
  __syncthreads();

  for (int kt = 0; kt < 16; ++kt) {
    const int cur = kt & 1;
    if (kt < 15) {
      const int kn = (kt + 1) * 32;
      gld_lds16(As[cur ^ 1] + c0 * 8, xb + (size_t)(m0 + ar0) * 512 + kn + ak0);
      gld_lds16(As[cur ^ 1] + c1 * 8, xb + (size_t)(m0 + ar1) * 512 + kn + ak1);
      gld_lds16(Bs[cur ^ 1] + c0 * 8, wqb + (size_t)(n0 + ar0) * 512 + kn + ak0);
      gld_lds16(Bs[cur ^ 1] + c1 * 8, wqb + (size_t)(n0 + ar1) * 512 + kn + ak1);
    }
    bf16x8 af[4], bfb[4];
#pragma unroll
    for (int mi = 0; mi < 4; ++mi)
      af[mi] = *(const bf16x8*)(As[cur] + (wr + mi * 16 + ln) * 32 + quad * 8);
#pragma unroll
    for (int ni = 0; ni < 4; ++ni)
      bfb[ni] = *(const bf16x8*)(Bs[cur] + (wc + ni * 16 + ln) * 32 + quad * 8);
#pragma unroll
    for (int mi = 0; mi < 4; ++mi)
#pragma unroll
      for (int ni = 0; ni < 4; ++ni)
        acc[mi][ni] = __builtin_amdgcn_mfma_f32_16x16x32_bf16(af[mi], bfb[ni], acc[mi][ni], 0, 0, 0);
    // barrier: (a) all waves done reading buf cur (overwritten next iter),
    // (b) implicit vmcnt(0) drain -> buf cur^1 staged for next iter.
    __syncthreads();
  }

  // epilogue: wave's 64 cols lie in exactly one (mat, head)
  const int colbase = n0 + wc;                    // multiple of 64
  const int mat = colbase >> 9;                   // 0=q 1=k 2=v
  const int h = (colbase & 511) >> 6;
  float bias[4];
#pragma unroll
  for (int ni = 0; ni < 4; ++ni) bias[ni] = qkv_b[colbase + ni * 16 + ln];

  if (mat == 2) {
    // V: store transposed (b,h,d,t); lane holds 4 consecutive t at fixed d
#pragma unroll
    for (int mi = 0; mi < 4; ++mi) {
      int row0 = m0 + wr + mi * 16 + quad * 4;
      int bidx = row0 >> 11, t = row0 & 2047;
#pragma unroll
      for (int ni = 0; ni < 4; ++ni) {
        int d = ni * 16 + ln;
        ushort4 pk;
        pk.x = f2bf(acc[mi][ni][0] + bias[ni]);
        pk.y = f2bf(acc[mi][ni][1] + bias[ni]);
        pk.z = f2bf(acc[mi][ni][2] + bias[ni]);
        pk.w = f2bf(acc[mi][ni][3] + bias[ni]);
        *(ushort4*)(Vtb + ((size_t)(bidx * 8 + h) * 64 + d) * 2048 + t) = pk;
      }
    }
  } else {
    // Q/K: in-register RoPE — pair (d, d+32) = acc tiles (ni, ni+2), same lane
    unsigned short* dst = (mat == 0) ? Qb : Kb;
    // fold 1/sqrt(64) AND log2(e) (exp2-domain softmax) into Q
    const float sc = (mat == 0) ? 0.125f * LOG2E : 1.0f;
#pragma unroll
    for (int mi = 0; mi < 4; ++mi) {
#pragma unroll
      for (int r = 0; r < 4; ++r) {
        int row = m0 + wr + mi * 16 + quad * 4 + r;
        int bidx = row >> 11, t = row & 2047;
        const float* cr = cosT + t * 32;
        const float* sr = sinT + t * 32;
        size_t obase = ((size_t)(bidx * 8 + h) * 2048 + t) * 64;
#pragma unroll
        for (int ni = 0; ni < 2; ++ni) {
          int dlo = ni * 16 + ln;
          float cv = cr[dlo], sv = sr[dlo];
          float xlo = acc[mi][ni][r] + bias[ni];
          float xhi = acc[mi][ni + 2][r] + bias[ni + 2];
          dst[obase + dlo]      = f2bf((xlo * cv - xhi * sv) * sc);
          dst[obase + dlo + 32] = f2bf((xhi * cv + xlo * sv) * sc);
        }
      }
    }
  }
}

// ---------------------------------------------------------------------------
// Transposed flash attention (round-3 proven version):
//   block = 128 q x one (b,h); 8 waves x 16 q each; K-tile = 64.
//   S^T = K·Q^T; XOR-swizzled 64-short LDS rows; cvt_pk P-pack; defer-rescale;
//   K/V staged via register prefetch.
// ---------------------------------------------------------------------------
__global__ __launch_bounds__(512) void attn_kernel(
    const unsigned short* __restrict__ Qb, const unsigned short* __restrict__ Kb,
    const unsigned short* __restrict__ Vtb, const float* __restrict__ mask,
    unsigned short* __restrict__ attnb) {
  __shared__ __align__(16) unsigned short Ks[64 * 64];   // (t_k, d)   swizzled
  __shared__ __align__(16) unsigned short Vs[64 * 64];   // (d, t_k)   swizzled
  __shared__ __align__(16) unsigned short Ps[128 * 64];  // (q, t_k)   swizzled

  const int tid = threadIdx.x;
  const int wave = tid >> 6, lane = tid & 63, ln = lane & 15, quad = lane >> 4;
  const int swz = (ln & 7) << 3;                 // row-derived XOR for frag reads
  const int bh = blockIdx.y;
  const int b = bh >> 3, h = bh & 7;
  const int q0 = blockIdx.x * 128;
  const int wq = wave * 16;                      // wave's local q base

  const unsigned short* Qhead = Qb + (size_t)bh * 2048 * 64;
  const unsigned short* Khead = Kb + (size_t)bh * 2048 * 64;
  const unsigned short* Vhead = Vtb + (size_t)bh * 64 * 2048;

  bf16x8 qf[2];
#pragma unroll
  for (int ks = 0; ks < 2; ++ks)
    qf[ks] = *(const bf16x8*)(Qhead + (size_t)(q0 + wq + ln) * 64 + ks * 32 + quad * 8);

  floatx4 o[4];   // O^T: [d-tile], lane col = q
#pragma unroll
  for (int mi2 = 0; mi2 < 4; ++mi2) o[mi2] = (floatx4){0.f, 0.f, 0.f, 0.f};
  float mrun = -INFINITY;
  float lrun = 0.f;

  const int srow = tid >> 3;                     // 0..63
  const int scol = (tid & 7) * 8;                // shorts
  const int sdst = srow * 64 + (scol ^ ((srow & 7) << 3));
  uint4 kpre = *(const uint4*)(Khead + (size_t)srow * 64 + scol);
  uint4 vpre = *(const uint4*)(Vhead + (size_t)srow * 2048 + scol);

  for (int k0 = 0; k0 < 2048; k0 += 64) {
    __syncthreads();   // prev-iter Ks/Vs reads done
    *(uint4*)(Ks + sdst) = kpre;
    *(uint4*)(Vs + sdst) = vpre;
    __syncthreads();   // staging visible
    if (k0 + 64 < 2048) {   // prefetch next tile; latency hidden by compute
      kpre = *(const uint4*)(Khead + (size_t)(k0 + 64 + srow) * 64 + scol);
      vpre = *(const uint4*)(Vhead + (size_t)srow * 2048 + k0 + 64 + scol);
    }

    // S^T = K·Q^T : A=K-frag A[m=t_k][k=d], B=Q. C: row=t_k(quad*4+r), col=q(ln)
    floatx4 sm[4];
#pragma unroll
    for (int mi = 0; mi < 4; ++mi) {
      bf16x8 kf0 = *(const bf16x8*)(Ks + (mi * 16 + ln) * 64 + ((quad * 8) ^ swz));
      bf16x8 kf1 = *(const bf16x8*)(Ks + (mi * 16 + ln) * 64 + ((32 + quad * 8) ^ swz));
      floatx4 a = (floatx4){0.f, 0.f, 0.f, 0.f};
      a = __builtin_amdgcn_mfma_f32_16x16x32_bf16(kf0, qf[0], a, 0, 0, 0);
      a = __builtin_amdgcn_mfma_f32_16x16x32_bf16(kf1, qf[1], a, 0, 0, 0);
      sm[mi] = a;
    }
#pragma unroll
    for (int mi = 0; mi < 4; ++mi) {
      float4 mv = *(const float4*)(mask + b * 2048 + k0 + mi * 16 + quad * 4);
      sm[mi][0] += mv.x * LOG2E; sm[mi][1] += mv.y * LOG2E;
      sm[mi][2] += mv.z * LOG2E; sm[mi][3] += mv.w * LOG2E;
    }
    // online softmax: per lane one q-column -> 15 in-reg max + 2 shuffles
    float vmax = fmaxf(fmaxf(sm[0][0], sm[0][1]), fmaxf(sm[0][2], sm[0][3]));
#pragma unroll
    for (int mi = 1; mi < 4; ++mi)
      vmax = fmaxf(vmax, fmaxf(fmaxf(sm[mi][0], sm[mi][1]), fmaxf(sm[mi][2], sm[mi][3])));
    vmax = fmaxf(vmax, __shfl_xor(vmax, 16));
    vmax = fmaxf(vmax, __shfl_xor(vmax, 32));
    // defer-rescale: only pay alpha/exp2/O-rescale when some lane's max grew
    if (__any(vmax > mrun)) {
      float nm = fmaxf(mrun, vmax);
      float alpha = exp2f(mrun - nm);   // lanes w/o growth: exp2(0)=1
      mrun = nm;
      lrun *= alpha;
#pragma unroll
      for (int mi2 = 0; mi2 < 4; ++mi2) {
        o[mi2][0] *= alpha; o[mi2][1] *= alpha;
        o[mi2][2] *= alpha; o[mi2][3] *= alpha;
      }
    }
    float psum = 0.f;
#pragma unroll
    for (int mi = 0; mi < 4; ++mi)
#pragma unroll
      for (int r = 0; r < 4; ++r) {
        float p = exp2f(sm[mi][r] - mrun);
        sm[mi][r] = p;
        psum += p;
      }
    psum += __shfl_xor(psum, 16);
    psum += __shfl_xor(psum, 32);
    lrun += psum;

    // P^T -> LDS (q, t_k): cvt_pk packed b64, per-wave rows, no barrier needed
#pragma unroll
    for (int mi = 0; mi < 4; ++mi) {
      uint2 pk;
      pk.x = cvtpk_bf16(sm[mi][0], sm[mi][1]);
      pk.y = cvtpk_bf16(sm[mi][2], sm[mi][3]);
      *(uint2*)(Ps + (wq + ln) * 64 + ((mi * 16 + quad * 4) ^ swz)) = pk;
    }
    // O^T += V^T·P : A=Vt-frag A[m=d][k=t_k], B=P-frag B[n=q][k=t_k]
#pragma unroll
    for (int ks = 0; ks < 2; ++ks) {
      bf16x8 pb = *(const bf16x8*)(Ps + (wq + ln) * 64 + ((ks * 32 + quad * 8) ^ swz));
#pragma unroll
      for (int mi2 = 0; mi2 < 4; ++mi2) {
        bf16x8 vf = *(const bf16x8*)(Vs + (mi2 * 16 + ln) * 64 + ((ks * 32 + quad * 8) ^ swz));
        o[mi2] = __builtin_amdgcn_mfma_f32_16x16x32_bf16(vf, pb, o[mi2], 0, 0, 0);
      }
    }
  }

  // epilogue: O^T lane owns q-col (1/l per-lane), 4 consecutive d per store
  {
    float inv = 1.f / lrun;
    int t = q0 + wq + ln;
    size_t base = ((size_t)b * 2048 + t) * 512 + h * 64;
#pragma unroll
    for (int mi2 = 0; mi2 < 4; ++mi2) {
      uint2 pk;
      pk.x = cvtpk_bf16(o[mi2][0] * inv, o[mi2][1] * inv);
      pk.y = cvtpk_bf16(o[mi2][2] * inv, o[mi2][3] * inv);
      *(uint2*)(attnb + base + mi2 * 16 + quad * 4) = pk;
    }
  }
}

// ---------------------------------------------------------------------------
// proj GEMM: attnb(8192x512) @ wpb(512x512)^T + bias -> out fp32
// 128x128 tile, 512 threads (8 waves x 32x64), 2-phase dbuf pipeline.
// Grid 256 blocks = 1 block/CU -> 8 waves/CU (was 4).
// ---------------------------------------------------------------------------
__global__ __launch_bounds__(512) void proj_kernel(
    const unsigned short* __restrict__ ab, const unsigned short* __restrict__ wpb,
    const float* __restrict__ proj_b, float* __restrict__ out) {
  __shared__ __align__(16) unsigned short As[2][128 * 32];
  __shared__ __align__(16) unsigned short Bs[2][128 * 32];
  const int tid = threadIdx.x;
  const int wave = tid >> 6, lane = tid & 63, ln = lane & 15, quad = lane >> 4;
  const int m0 = blockIdx.x * 128, n0 = blockIdx.y * 128;
  const int wr = (wave >> 1) * 32, wc = (wave & 1) * 64;

  floatx4 acc[2][4];
#pragma unroll
  for (int i = 0; i < 2; ++i)
#pragma unroll
    for (int j = 0; j < 4; ++j) acc[i][j] = (floatx4){0.f, 0.f, 0.f, 0.f};

  // 512 threads stage 512 x 16B chunks of each tile (1 A + 1 B per thread)
  const int ar = tid >> 2, ak = (tid & 3) * 8;

  gld_lds16(As[0] + tid * 8, ab + (size_t)(m0 + ar) * 512 + ak);
  gld_lds16(Bs[0] + tid * 8, wpb + (size_t)(n0 + ar) * 512 + ak);
  __syncthreads();

  for (int kt = 0; kt < 16; ++kt) {
    const int cur = kt & 1;
    if (kt < 15) {
      const int kn = (kt + 1) * 32;
      gld_lds16(As[cur ^ 1] + tid * 8, ab + (size_t)(m0 + ar) * 512 + kn + ak);
      gld_lds16(Bs[cur ^ 1] + tid * 8, wpb + (size_t)(n0 + ar) * 512 + kn + ak);
    }
    bf16x8 af[2], bfb[4];
#pragma unroll
    for (int mi = 0; mi < 2; ++mi)
      af[mi] = *(const bf16x8*)(As[cur] + (wr + mi * 16 + ln) * 32 + quad * 8);
#pragma unroll
    for (int ni = 0; ni < 4; ++ni)
      bfb[ni] = *(const bf16x8*)(Bs[cur] + (wc + ni * 16 + ln) * 32 + quad * 8);
#pragma unroll
    for (int mi = 0; mi < 2; ++mi)
#pragma unroll
      for (int ni = 0; ni < 4; ++ni)
        acc[mi][ni] = __builtin_amdgcn_mfma_f32_16x16x32_bf16(af[mi], bfb[ni], acc[mi][ni], 0, 0, 0);
    __syncthreads();
  }

#pragma unroll
  for (int mi = 0; mi < 2; ++mi)
#pragma unroll
    for (int ni = 0; ni < 4; ++ni) {
      int col = n0 + wc + ni * 16 + ln;
      float pb = proj_b[col];
#pragma unroll
      for (int r = 0; r < 4; ++r) {
        int row = m0 + wr + mi * 16 + quad * 4 + r;
        out[(size_t)row * 512 + col] = acc[mi][ni][r] + pb;
      }
    }
}

// ---------------------------------------------------------------------------
extern "C" void kernel_launch(void* const* d_in, const int* in_sizes, int n_in,
                              void* d_out, int out_size, void* d_ws, size_t ws_size,
                              hipStream_t stream) {
  const float* x      = (const float*)d_in[0];
  const float* mask   = (const float*)d_in[1];
  const float* qkv_w  = (const float*)d_in[2];
  const float* qkv_b  = (const float*)d_in[3];
  const float* proj_w = (const float*)d_in[4];
  const float* proj_b = (const float*)d_in[5];
  float* out = (float*)d_out;

  char* ws = (char*)d_ws;
  unsigned short* xb   = (unsigned short*)(ws);
  unsigned short* wqb  = (unsigned short*)(ws + 8388608);
  unsigned short* wpb  = (unsigned short*)(ws + 9961472);
  float* cosT          = (float*)(ws + 10485760);
  float* sinT          = (float*)(ws + 10747904);
  unsigned short* Qb   = (unsigned short*)(ws + 11010048);
  unsigned short* Kb   = (unsigned short*)(ws + 19398656);
  unsigned short* Vtb  = (unsigned short*)(ws + 27787264);
  unsigned short* attnb= (unsigned short*)(ws + 36175872);

  prep_kernel<<<2816, 256, 0, stream>>>(x, qkv_w, proj_w, xb, wqb, wpb, cosT, sinT);
  dim3 g1(64, 12);
  qkv_kernel<<<g1, 256, 0, stream>>>(xb, wqb, qkv_b, cosT, sinT, Qb, Kb, Vtb);
  dim3 g2(16, 32);
  attn_kernel<<<g2, 512, 0, stream>>>(Qb, Kb, Vtb, mask, attnb);
  dim3 g3(64, 4);
  proj_kernel<<<g3, 512, 0, stream>>>(attnb, wpb, proj_b, out);
}

// Round 5
// 185.654 us; speedup vs baseline: 1.1300x; 1.0602x over previous
//
#include <hip/hip_runtime.h>
#include <math.h>

// ---------------------------------------------------------------------------
// HROMAttention: x(4,2048,512) -> QKV(+bias) -> RoPE -> MHA(8 heads, d=64)
//                -> proj(+bias). All GEMMs bf16 MFMA 16x16x32, fp32 accum.
// Round 6:
//   - attn: single-barrier double-buffered K/V staging (was 2 barriers/tile).
//     LDS 48KB (Ks[2]+Vs[2]+Ps), still >=2 wg/CU.
//   - qkv: V epilogue transposed through LDS (reuse dead GEMM tiles) ->
//     coalesced 16B stores along t (was 8B stores at 4096B lane stride).
//   - prep/proj unchanged from round 5 (passed).
// ws layout (bytes):
//   [0)         xb     bf16 8192x512     8388608
//   [8388608)   wqb    bf16 1536x512     1572864
//   [9961472)   wpb    bf16  512x512      524288
//   [10485760)  cosT   f32  2048x32       262144
//   [10747904)  sinT   f32  2048x32       262144
//   [11010048)  Qb     bf16 (b,h,t,d)    8388608   (pre-scaled by 0.125*log2e)
//   [19398656)  Kb     bf16 (b,h,t,d)    8388608
//   [27787264)  Vtb    bf16 (b,h,d,t)    8388608
//   [36175872)  attnb  bf16 8192x512     8388608
// total 44564480 B (~42.5 MB) of d_ws
// ---------------------------------------------------------------------------

typedef __attribute__((ext_vector_type(8))) short bf16x8;
typedef __attribute__((ext_vector_type(4))) float floatx4;

#define LOG2E 1.44269504088896f

__device__ __forceinline__ unsigned short f2bf(float f) {
  unsigned int u = __float_as_uint(f);
  u += 0x7fffu + ((u >> 16) & 1u);   // round-to-nearest-even
  return (unsigned short)(u >> 16);
}

// pack two f32 -> bf16x2 (low16 = a, high16 = b), RNE, single VALU inst
__device__ __forceinline__ unsigned int cvtpk_bf16(float a, float b) {
  unsigned int r;
  asm("v_cvt_pk_bf16_f32 %0, %1, %2" : "=v"(r) : "v"(a), "v"(b));
  return r;
}

__device__ __forceinline__ void gld_lds16(unsigned short* lds, const unsigned short* g) {
  __builtin_amdgcn_global_load_lds(
      (const __attribute__((address_space(1))) unsigned int*)g,
      (__attribute__((address_space(3))) unsigned int*)lds, 16, 0, 0);
}

// ---------------------------------------------------------------------------
// prep: bf16 conversions (8 elems/thread) + RoPE cos/sin table (fp64 trig)
// f32 elements: x 4194304 | wq 786432 | wp 262144  (all /8) -> 655360 threads
// table: 65536 entries, 1/thread -> threads 655360..720895
// ---------------------------------------------------------------------------
__global__ __launch_bounds__(256) void prep_kernel(
    const float* __restrict__ x, const float* __restrict__ wq, const float* __restrict__ wp,
    unsigned short* __restrict__ xb, unsigned short* __restrict__ wqb,
    unsigned short* __restrict__ wpb, float* __restrict__ cosT, float* __restrict__ sinT) {
  int i = blockIdx.x * 256 + threadIdx.x;
  if (i < 655360) {
    int base = i * 8;
    const float* src;
    unsigned short* dst;
    int j;
    if (base < 4194304)      { src = x;  dst = xb;  j = base; }
    else if (base < 4980736) { src = wq; dst = wqb; j = base - 4194304; }
    else                     { src = wp; dst = wpb; j = base - 4980736; }
    float4 a = *(const float4*)(src + j);
    float4 b = *(const float4*)(src + j + 4);
    uint4 r;
    r.x = cvtpk_bf16(a.x, a.y);
    r.y = cvtpk_bf16(a.z, a.w);
    r.z = cvtpk_bf16(b.x, b.y);
    r.w = cvtpk_bf16(b.z, b.w);
    *(uint4*)(dst + j) = r;
  } else if (i < 720896) {
    int j = i - 655360;
    int t = j >> 5, f = j & 31;
    double fr = (double)t * pow(10000.0, -(double)f / 32.0);
    cosT[j] = (float)cos(fr);
    sinT[j] = (float)sin(fr);
  }
}

// ---------------------------------------------------------------------------
// QKV GEMM: xb(8192x512) @ wqb(1536x512)^T + bias, epilogue RoPE + scatter
// 128x128 tile, BK=32, 4 waves each 64x64. 2-phase dbuf pipeline.
// V-blocks (mat==2, block-uniform) transpose their output through the dead
// GEMM LDS (32 KB) for coalesced stores along t.
// ---------------------------------------------------------------------------
__global__ __launch_bounds__(256) void qkv_kernel(
    const unsigned short* __restrict__ xb, const unsigned short* __restrict__ wqb,
    const float* __restrict__ qkv_b, const float* __restrict__ cosT,
    const float* __restrict__ sinT, unsigned short* __restrict__ Qb,
    unsigned short* __restrict__ Kb, unsigned short* __restrict__ Vtb) {
  // [buf][A=0/B=1][128*32] ; also reused as 32 KB transpose buffer (V epilogue)
  __shared__ __align__(16) unsigned short SM[2][2][128 * 32];
  const int tid = threadIdx.x;
  const int wave = tid >> 6, lane = tid & 63, ln = lane & 15, quad = lane >> 4;
  const int m0 = blockIdx.x * 128, n0 = blockIdx.y * 128;
  const int wr = (wave >> 1) * 64, wc = (wave & 1) * 64;

  floatx4 acc[4][4];
#pragma unroll
  for (int i = 0; i < 4; ++i)
#pragma unroll
    for (int j = 0; j < 4; ++j) acc[i][j] = (floatx4){0.f, 0.f, 0.f, 0.f};

  const int c0 = tid, c1 = tid + 256;
  const int ar0 = c0 >> 2, ak0 = (c0 & 3) * 8;
  const int ar1 = c1 >> 2, ak1 = (c1 & 3) * 8;

  // prologue: stage K-tile 0 into buffer 0
  gld_lds16(SM[0][0] + c0 * 8, xb + (size_t)(m0 + ar0) * 512 + ak0);
  gld_lds16(SM[0][0] + c1 * 8, xb + (size_t)(m0 + ar1) * 512 + ak1);
  gld_lds16(SM[0][1] + c0 * 8, wqb + (size_t)(n0 + ar0) * 512 + ak0);
  gld_lds16(SM[0][1] + c1 * 8, wqb + (size_t)(n0 + ar1) * 512 + ak1);
  __syncthreads();

  for (int kt = 0; kt < 16; ++kt) {
    const int cur = kt & 1;
    if (kt < 15) {
      const int kn = (kt + 1) * 32;
      gld_lds16(SM[cur ^ 1][0] + c0 * 8, xb + (size_t)(m0 + ar0) * 512 + kn + ak0);
      gld_lds16(SM[cur ^ 1][0] + c1 * 8, xb + (size_t)(m0 + ar1) * 512 + kn + ak1);
      gld_lds16(SM[cur ^ 1][1] + c0 * 8, wqb + (size_t)(n0 + ar0) * 512 + kn + ak0);
      gld_lds16(SM[cur ^ 1][1] + c1 * 8, wqb + (size_t)(n0 + ar1) * 512 + kn + ak1);
    }
    bf16x8 af[4], bfb[4];
#pragma unroll
    for (int mi = 0; mi < 4; ++mi)
      af[mi] = *(const bf16x8*)(SM[cur][0] + (wr + mi * 16 + ln) * 32 + quad * 8);
#pragma unroll
    for (int ni = 0; ni < 4; ++ni)
      bfb[ni] = *(const bf16x8*)(SM[cur][1] + (wc + ni * 16 + ln) * 32 + quad * 8);
#pragma unroll
    for (int mi = 0; mi < 4; ++mi)
#pragma unroll
      for (int ni = 0; ni < 4; ++ni)
        acc[mi][ni] = __builtin_amdgcn_mfma_f32_16x16x32_bf16(af[mi], bfb[ni], acc[mi][ni], 0, 0, 0);
    __syncthreads();
  }

  // epilogue: wave's 64 cols lie in exactly one (mat, head); mat is
  // block-uniform (128-col block within one 512-col matrix region).
  const int colbase = n0 + wc;                    // multiple of 64
  const int mat = colbase >> 9;                   // 0=q 1=k 2=v
  float bias[4];
#pragma unroll
  for (int ni = 0; ni < 4; ++ni) bias[ni] = qkv_b[colbase + ni * 16 + ln];

  if (mat == 2) {
    // V: transpose through LDS -> coalesced (d,t) stores.
    // Ts[c][r], c = local col (head*64+d) 0..127, r = local t 0..127,
    // phys short index = c*128 + (r ^ ((c&7)<<3))   (bank-spread swizzle)
    unsigned short* Ts = &SM[0][0][0];             // 32 KB, GEMM tiles dead
#pragma unroll
    for (int mi = 0; mi < 4; ++mi) {
      int r0 = wr + mi * 16 + quad * 4;            // 4 consecutive t
#pragma unroll
      for (int ni = 0; ni < 4; ++ni) {
        int c = wc + ni * 16 + ln;
        ushort4 pk;
        pk.x = f2bf(acc[mi][ni][0] + bias[ni]);
        pk.y = f2bf(acc[mi][ni][1] + bias[ni]);
        pk.z = f2bf(acc[mi][ni][2] + bias[ni]);
        pk.w = f2bf(acc[mi][ni][3] + bias[ni]);
        *(ushort4*)(Ts + c * 128 + (r0 ^ ((c & 7) << 3))) = pk;
      }
    }
    __syncthreads();
    // write out: thread -> (d2 = tid>>1, seg = tid&1); 64 shorts along t
    const int d2 = tid >> 1, seg = tid & 1;
    const int h0 = (n0 & 511) >> 6;                // first head in block
    const int hh = d2 >> 6, dd = d2 & 63;
    const int bidx = m0 >> 11, tl0 = m0 & 2047;    // block spans one batch
    unsigned short* dst = Vtb + ((size_t)(bidx * 8 + h0 + hh) * 64 + dd) * 2048 + tl0;
    const int xr = (d2 & 7) << 3;
#pragma unroll
    for (int j = 0; j < 8; ++j) {
      int g = seg * 64 + j * 8;                    // granule-aligned (8 shorts)
      uint4 v = *(const uint4*)(Ts + d2 * 128 + (g ^ xr));
      *(uint4*)(dst + g) = v;
    }
  } else {
    // Q/K: in-register RoPE — pair (d, d+32) = acc tiles (ni, ni+2), same lane
    const int h = (colbase & 511) >> 6;
    unsigned short* dst = (mat == 0) ? Qb : Kb;
    // fold 1/sqrt(64) AND log2(e) (exp2-domain softmax) into Q
    const float sc = (mat == 0) ? 0.125f * LOG2E : 1.0f;
#pragma unroll
    for (int mi = 0; mi < 4; ++mi) {
#pragma unroll
      for (int r = 0; r < 4; ++r) {
        int row = m0 + wr + mi * 16 + quad * 4 + r;
        int bidx = row >> 11, t = row & 2047;
        const float* cr = cosT + t * 32;
        const float* sr = sinT + t * 32;
        size_t obase = ((size_t)(bidx * 8 + h) * 2048 + t) * 64;
#pragma unroll
        for (int ni = 0; ni < 2; ++ni) {
          int dlo = ni * 16 + ln;
          float cv = cr[dlo], sv = sr[dlo];
          float xlo = acc[mi][ni][r] + bias[ni];
          float xhi = acc[mi][ni + 2][r] + bias[ni + 2];
          dst[obase + dlo]      = f2bf((xlo * cv - xhi * sv) * sc);
          dst[obase + dlo + 32] = f2bf((xhi * cv + xlo * sv) * sc);
        }
      }
    }
  }
}

// ---------------------------------------------------------------------------
// Transposed flash attention, round 6: single-barrier double-buffered K/V.
//   block = 128 q x one (b,h); 8 waves x 16 q each; K-tile = 64.
//   S^T = K·Q^T; XOR-swizzled 64-short LDS rows; cvt_pk P-pack; defer-rescale.
//   Loop: prefetch regs(t+1) -> compute from buf[cur] -> write buf[cur^1]
//   -> ONE barrier (was stage-barrier-compute-barrier).
// ---------------------------------------------------------------------------
__global__ __launch_bounds__(512) void attn_kernel(
    const unsigned short* __restrict__ Qb, const unsigned short* __restrict__ Kb,
    const unsigned short* __restrict__ Vtb, const float* __restrict__ mask,
    unsigned short* __restrict__ attnb) {
  __shared__ __align__(16) unsigned short Ks[2][64 * 64];  // (t_k, d) swizzled
  __shared__ __align__(16) unsigned short Vs[2][64 * 64];  // (d, t_k) swizzled
  __shared__ __align__(16) unsigned short Ps[128 * 64];    // (q, t_k) swizzled

  const int tid = threadIdx.x;
  const int wave = tid >> 6, lane = tid & 63, ln = lane & 15, quad = lane >> 4;
  const int swz = (ln & 7) << 3;                 // row-derived XOR for frag reads
  const int bh = blockIdx.y;
  const int b = bh >> 3, h = bh & 7;
  const int q0 = blockIdx.x * 128;
  const int wq = wave * 16;                      // wave's local q base

  const unsigned short* Qhead = Qb + (size_t)bh * 2048 * 64;
  const unsigned short* Khead = Kb + (size_t)bh * 2048 * 64;
  const unsigned short* Vhead = Vtb + (size_t)bh * 64 * 2048;

  bf16x8 qf[2];
#pragma unroll
  for (int ks = 0; ks < 2; ++ks)
    qf[ks] = *(const bf16x8*)(Qhead + (size_t)(q0 + wq + ln) * 64 + ks * 32 + quad * 8);

  floatx4 o[4];   // O^T: [d-tile], lane col = q
#pragma unroll
  for (int mi2 = 0; mi2 < 4; ++mi2) o[mi2] = (floatx4){0.f, 0.f, 0.f, 0.f};
  float mrun = -INFINITY;
  float lrun = 0.f;

  const int srow = tid >> 3;                     // 0..63
  const int scol = (tid & 7) * 8;                // shorts
  const int sdst = srow * 64 + (scol ^ ((srow & 7) << 3));

  // prologue: tile 0 -> regs -> buf 0
  {
    uint4 k0v = *(const uint4*)(Khead + (size_t)srow * 64 + scol);
    uint4 v0v = *(const uint4*)(Vhead + (size_t)srow * 2048 + scol);
    *(uint4*)(Ks[0] + sdst) = k0v;
    *(uint4*)(Vs[0] + sdst) = v0v;
  }
  __syncthreads();

  for (int kt = 0; kt < 32; ++kt) {
    const int cur = kt & 1;
    const int k0 = kt * 64;
    uint4 kpre, vpre;
    if (kt < 31) {   // prefetch next tile; latency hidden by compute below
      kpre = *(const uint4*)(Khead + (size_t)(k0 + 64 + srow) * 64 + scol);
      vpre = *(const uint4*)(Vhead + (size_t)srow * 2048 + k0 + 64 + scol);
    }

    // S^T = K·Q^T : A=K-frag A[m=t_k][k=d], B=Q. C: row=t_k(quad*4+r), col=q(ln)
    floatx4 sm[4];
#pragma unroll
    for (int mi = 0; mi < 4; ++mi) {
      bf16x8 kf0 = *(const bf16x8*)(Ks[cur] + (mi * 16 + ln) * 64 + ((quad * 8) ^ swz));
      bf16x8 kf1 = *(const bf16x8*)(Ks[cur] + (mi * 16 + ln) * 64 + ((32 + quad * 8) ^ swz));
      floatx4 a = (floatx4){0.f, 0.f, 0.f, 0.f};
      a = __builtin_amdgcn_mfma_f32_16x16x32_bf16(kf0, qf[0], a, 0, 0, 0);
      a = __builtin_amdgcn_mfma_f32_16x16x32_bf16(kf1, qf[1], a, 0, 0, 0);
      sm[mi] = a;
    }
#pragma unroll
    for (int mi = 0; mi < 4; ++mi) {
      float4 mv = *(const float4*)(mask + b * 2048 + k0 + mi * 16 + quad * 4);
      sm[mi][0] += mv.x * LOG2E; sm[mi][1] += mv.y * LOG2E;
      sm[mi][2] += mv.z * LOG2E; sm[mi][3] += mv.w * LOG2E;
    }
    // online softmax: per lane one q-column -> 15 in-reg max + 2 shuffles
    float vmax = fmaxf(fmaxf(sm[0][0], sm[0][1]), fmaxf(sm[0][2], sm[0][3]));
#pragma unroll
    for (int mi = 1; mi < 4; ++mi)
      vmax = fmaxf(vmax, fmaxf(fmaxf(sm[mi][0], sm[mi][1]), fmaxf(sm[mi][2], sm[mi][3])));
    vmax = fmaxf(vmax, __shfl_xor(vmax, 16));
    vmax = fmaxf(vmax, __shfl_xor(vmax, 32));
    // defer-rescale: only pay alpha/exp2/O-rescale when some lane's max grew
    if (__any(vmax > mrun)) {
      float nm = fmaxf(mrun, vmax);
      float alpha = exp2f(mrun - nm);   // lanes w/o growth: exp2(0)=1
      mrun = nm;
      lrun *= alpha;
#pragma unroll
      for (int mi2 = 0; mi2 < 4; ++mi2) {
        o[mi2][0] *= alpha; o[mi2][1] *= alpha;
        o[mi2][2] *= alpha; o[mi2][3] *= alpha;
      }
    }
    float psum = 0.f;
#pragma unroll
    for (int mi = 0; mi < 4; ++mi)
#pragma unroll
      for (int r = 0; r < 4; ++r) {
        float p = exp2f(sm[mi][r] - mrun);
        sm[mi][r] = p;
        psum += p;
      }
    psum += __shfl_xor(psum, 16);
    psum += __shfl_xor(psum, 32);
    lrun += psum;

    // P^T -> LDS (q, t_k): cvt_pk packed b64, per-wave rows, no barrier needed
#pragma unroll
    for (int mi = 0; mi < 4; ++mi) {
      uint2 pk;
      pk.x = cvtpk_bf16(sm[mi][0], sm[mi][1]);
      pk.y = cvtpk_bf16(sm[mi][2], sm[mi][3]);
      *(uint2*)(Ps + (wq + ln) * 64 + ((mi * 16 + quad * 4) ^ swz)) = pk;
    }
    // O^T += V^T·P : A=Vt-frag A[m=d][k=t_k], B=P-frag B[n=q][k=t_k]
#pragma unroll
    for (int ks = 0; ks < 2; ++ks) {
      bf16x8 pb = *(const bf16x8*)(Ps + (wq + ln) * 64 + ((ks * 32 + quad * 8) ^ swz));
#pragma unroll
      for (int mi2 = 0; mi2 < 4; ++mi2) {
        bf16x8 vf = *(const bf16x8*)(Vs[cur] + (mi2 * 16 + ln) * 64 + ((ks * 32 + quad * 8) ^ swz));
        o[mi2] = __builtin_amdgcn_mfma_f32_16x16x32_bf16(vf, pb, o[mi2], 0, 0, 0);
      }
    }

    // stage next tile into the other buffer; visible after the single barrier.
    // Safe: all waves' reads of buf[cur^1] finished before the PREVIOUS barrier.
    if (kt < 31) {
      *(uint4*)(Ks[cur ^ 1] + sdst) = kpre;
      *(uint4*)(Vs[cur ^ 1] + sdst) = vpre;
      __syncthreads();
    }
  }

  // epilogue: O^T lane owns q-col (1/l per-lane), 4 consecutive d per store
  {
    float inv = 1.f / lrun;
    int t = q0 + wq + ln;
    size_t base = ((size_t)b * 2048 + t) * 512 + h * 64;
#pragma unroll
    for (int mi2 = 0; mi2 < 4; ++mi2) {
      uint2 pk;
      pk.x = cvtpk_bf16(o[mi2][0] * inv, o[mi2][1] * inv);
      pk.y = cvtpk_bf16(o[mi2][2] * inv, o[mi2][3] * inv);
      *(uint2*)(attnb + base + mi2 * 16 + quad * 4) = pk;
    }
  }
}

// ---------------------------------------------------------------------------
// proj GEMM: attnb(8192x512) @ wpb(512x512)^T + bias -> out fp32
// 128x128 tile, 512 threads (8 waves x 32x64), 2-phase dbuf pipeline.
// ---------------------------------------------------------------------------
__global__ __launch_bounds__(512) void proj_kernel(
    const unsigned short* __restrict__ ab, const unsigned short* __restrict__ wpb,
    const float* __restrict__ proj_b, float* __restrict__ out) {
  __shared__ __align__(16) unsigned short As[2][128 * 32];
  __shared__ __align__(16) unsigned short Bs[2][128 * 32];
  const int tid = threadIdx.x;
  const int wave = tid >> 6, lane = tid & 63, ln = lane & 15, quad = lane >> 4;
  const int m0 = blockIdx.x * 128, n0 = blockIdx.y * 128;
  const int wr = (wave >> 1) * 32, wc = (wave & 1) * 64;

  floatx4 acc[2][4];
#pragma unroll
  for (int i = 0; i < 2; ++i)
#pragma unroll
    for (int j = 0; j < 4; ++j) acc[i][j] = (floatx4){0.f, 0.f, 0.f, 0.f};

  // 512 threads stage 512 x 16B chunks of each tile (1 A + 1 B per thread)
  const int ar = tid >> 2, ak = (tid & 3) * 8;

  gld_lds16(As[0] + tid * 8, ab + (size_t)(m0 + ar) * 512 + ak);
  gld_lds16(Bs[0] + tid * 8, wpb + (size_t)(n0 + ar) * 512 + ak);
  __syncthreads();

  for (int kt = 0; kt < 16; ++kt) {
    const int cur = kt & 1;
    if (kt < 15) {
      const int kn = (kt + 1) * 32;
      gld_lds16(As[cur ^ 1] + tid * 8, ab + (size_t)(m0 + ar) * 512 + kn + ak);
      gld_lds16(Bs[cur ^ 1] + tid * 8, wpb + (size_t)(n0 + ar) * 512 + kn + ak);
    }
    bf16x8 af[2], bfb[4];
#pragma unroll
    for (int mi = 0; mi < 2; ++mi)
      af[mi] = *(const bf16x8*)(As[cur] + (wr + mi * 16 + ln) * 32 + quad * 8);
#pragma unroll
    for (int ni = 0; ni < 4; ++ni)
      bfb[ni] = *(const bf16x8*)(Bs[cur] + (wc + ni * 16 + ln) * 32 + quad * 8);
#pragma unroll
    for (int mi = 0; mi < 2; ++mi)
#pragma unroll
      for (int ni = 0; ni < 4; ++ni)
        acc[mi][ni] = __builtin_amdgcn_mfma_f32_16x16x32_bf16(af[mi], bfb[ni], acc[mi][ni], 0, 0, 0);
    __syncthreads();
  }

#pragma unroll
  for (int mi = 0; mi < 2; ++mi)
#pragma unroll
    for (int ni = 0; ni < 4; ++ni) {
      int col = n0 + wc + ni * 16 + ln;
      float pb = proj_b[col];
#pragma unroll
      for (int r = 0; r < 4; ++r) {
        int row = m0 + wr + mi * 16 + quad * 4 + r;
        out[(size_t)row * 512 + col] = acc[mi][ni][r] + pb;
      }
    }
}

// ---------------------------------------------------------------------------
extern "C" void kernel_launch(void* const* d_in, const int* in_sizes, int n_in,
                              void* d_out, int out_size, void* d_ws, size_t ws_size,
                              hipStream_t stream) {
  const float* x      = (const float*)d_in[0];
  const float* mask   = (const float*)d_in[1];
  const float* qkv_w  = (const float*)d_in[2];
  const float* qkv_b  = (const float*)d_in[3];
  const float* proj_w = (const float*)d_in[4];
  const float* proj_b = (const float*)d_in[5];
  float* out = (float*)d_out;

  char* ws = (char*)d_ws;
  unsigned short* xb   = (unsigned short*)(ws);
  unsigned short* wqb  = (unsigned short*)(ws + 8388608);
  unsigned short* wpb  = (unsigned short*)(ws + 9961472);
  float* cosT          = (float*)(ws + 10485760);
  float* sinT          = (float*)(ws + 10747904);
  unsigned short* Qb   = (unsigned short*)(ws + 11010048);
  unsigned short* Kb   = (unsigned short*)(ws + 19398656);
  unsigned short* Vtb  = (unsigned short*)(ws + 27787264);
  unsigned short* attnb= (unsigned short*)(ws + 36175872);

  prep_kernel<<<2816, 256, 0, stream>>>(x, qkv_w, proj_w, xb, wqb, wpb, cosT, sinT);
  dim3 g1(64, 12);
  qkv_kernel<<<g1, 256, 0, stream>>>(xb, wqb, qkv_b, cosT, sinT, Qb, Kb, Vtb);
  dim3 g2(16, 32);
  attn_kernel<<<g2, 512, 0, stream>>>(Qb, Kb, Vtb, mask, attnb);
  dim3 g3(64, 4);
  proj_kernel<<<g3, 512, 0, stream>>>(attnb, wpb, proj_b, out);
}